// Round 6
// baseline (607.848 us; speedup 1.0000x reference)
//
#include <hip/hip_runtime.h>

// ---------------------------------------------------------------------------
// BlockGNN on MI355X, round 8:
//   - aggregate: XCD-channel-sliced gather. slice = blockIdx % NSLICE maps all
//     blocks of one slice to one XCD (round-robin dispatch), so each XCD's L2
//     holds only its 3.2MB slice of u -> kills the 8x L2-duplication fetch
//     (rounds 4-6: FETCH 186MB vs 25.6MB working set, 3.7 TB/s plateau).
//     4-lane group owns one node's 64B slice; serial edge loop; no shuffles.
//   - GEMM: reverted to round-4 LDS BM=128/512thr (round-7 LDS-free regressed
//     +12.5us/layer: scattered fragment loads, no reuse amortization).
// ---------------------------------------------------------------------------

typedef __bf16 bf16x8 __attribute__((ext_vector_type(8)));
typedef float f32x4 __attribute__((ext_vector_type(4)));

__device__ inline float bf2f(unsigned short u) {
  union { unsigned int i; float f; } v;
  v.i = (unsigned int)u << 16;
  return v.f;
}
__device__ inline unsigned short f2bf(float f) {
  union { unsigned int i; float f; } v;
  v.f = f;
  unsigned int i = v.i;
  return (unsigned short)((i + 0x7fffu + ((i >> 16) & 1u)) >> 16);  // RNE
}
__device__ inline unsigned int pack2(float a, float b) {
  return (unsigned int)f2bf(a) | ((unsigned int)f2bf(b) << 16);
}
__device__ inline void acc8(float* acc, uint4 r) {
  unsigned int w[4] = {r.x, r.y, r.z, r.w};
#pragma unroll
  for (int q = 0; q < 4; ++q) {
    acc[2 * q] += bf2f((unsigned short)(w[q] & 0xffffu));
    acc[2 * q + 1] += bf2f((unsigned short)(w[q] >> 16));
  }
}

// ----------------------------- CSR build -----------------------------------

__global__ void count_deg_kernel(const int* __restrict__ dst, int* __restrict__ deg, int E) {
  int e = blockIdx.x * blockDim.x + threadIdx.x;
  if (e < E) atomicAdd(&deg[dst[e]], 1);
}

// fused: per-block degree sums for the scan + inv_s = rsqrt(deg+1)
__global__ void scan_partial_kernel(const int* __restrict__ deg, float* __restrict__ inv_s,
                                    int* __restrict__ bsum, int N) {
  __shared__ int s[256];
  int i = blockIdx.x * 256 + threadIdx.x;
  int d = (i < N) ? deg[i] : 0;
  if (i < N) inv_s[i] = rsqrtf((float)(d + 1));  // +1 self loop
  s[threadIdx.x] = d;
  __syncthreads();
  for (int off = 128; off > 0; off >>= 1) {
    if (threadIdx.x < off) s[threadIdx.x] += s[threadIdx.x + off];
    __syncthreads();
  }
  if (threadIdx.x == 0) bsum[blockIdx.x] = s[0];
}

__global__ void scan_block_kernel(const int* __restrict__ bsum, int* __restrict__ boff,
                                  int* __restrict__ row_off, int NB, int N) {
  __shared__ int s[256];
  int v = (threadIdx.x < NB) ? bsum[threadIdx.x] : 0;
  s[threadIdx.x] = v;
  __syncthreads();
  for (int off = 1; off < 256; off <<= 1) {
    int t = (threadIdx.x >= off) ? s[threadIdx.x - off] : 0;
    __syncthreads();
    s[threadIdx.x] += t;
    __syncthreads();
  }
  boff[threadIdx.x] = s[threadIdx.x] - v;
  if (threadIdx.x == 255) row_off[N] = s[255];
}

__global__ void scan_final_kernel(const int* __restrict__ deg, const int* __restrict__ boff,
                                  int* __restrict__ row_off, int N) {
  __shared__ int s[256];
  int i = blockIdx.x * 256 + threadIdx.x;
  int v = (i < N) ? deg[i] : 0;
  s[threadIdx.x] = v;
  __syncthreads();
  for (int off = 1; off < 256; off <<= 1) {
    int t = (threadIdx.x >= off) ? s[threadIdx.x - off] : 0;
    __syncthreads();
    s[threadIdx.x] += t;
    __syncthreads();
  }
  if (i < N) row_off[i] = boff[blockIdx.x] + s[threadIdx.x] - v;
}

__global__ void fill_csr_kernel(const int* __restrict__ src, const int* __restrict__ dst,
                                const int* __restrict__ row_off, int* __restrict__ cursor,
                                int* __restrict__ col, int E) {
  int e = blockIdx.x * blockDim.x + threadIdx.x;
  if (e < E) {
    int d = dst[e];
    int pos = atomicAdd(&cursor[d], 1);
    col[row_off[d] + pos] = src[e];
  }
}

// ----------------------------- prep ----------------------------------------

// u_x[i][c] = bf16( inv_s[i] * x[i][c] ),  CH = 128
__global__ void prep_ux_kernel(const float* __restrict__ x, const float* __restrict__ inv_s,
                               unsigned short* __restrict__ u, int total) {
  int idx = blockIdx.x * 256 + threadIdx.x;
  if (idx < total) {
    int i = idx >> 7;
    u[idx] = f2bf(inv_s[i] * x[idx]);
  }
}

// single kernel transposing W0 [128][256] and 3x Ws [256][256] to bf16
__global__ void transpose_all_kernel(const float* __restrict__ W0, const float* __restrict__ Ws,
                                     unsigned short* __restrict__ Wt0,
                                     unsigned short* __restrict__ WtS) {
  const int FH = 128 * 256, HH = 256 * 256;
  int idx = blockIdx.x * 256 + threadIdx.x;
  if (idx < FH) {
    int k = idx >> 8, n = idx & 255;
    Wt0[n * 128 + k] = f2bf(W0[idx]);
  } else {
    int t = idx - FH;
    if (t < 3 * HH) {
      int l = t >> 16;
      int rem = t & 65535;
      int k = rem >> 8, n = rem & 255;
      WtS[l * HH + n * 256 + k] = f2bf(Ws[t]);
    }
  }
}

// ----------------------------- aggregate (XCD-sliced) ------------------------
// out_i[slice] = bf16( s_i * ( u_i[slice] + sum_{j in in(i)} u_j[slice] ) )
// NSLICE = CH/32 slices of 32 channels (64B = one cache line). slice =
// blockIdx % NSLICE: with round-robin workgroup->XCD dispatch all blocks of a
// slice land on one XCD, whose L2 then only holds that 3.2MB slice of u.
// Each 4-lane group owns one node's 64B slice; serial (2-unrolled) edge loop;
// no cross-lane reduction at all.
template <int CH>
__global__ __launch_bounds__(256) void aggregate_sliced_kernel(
    const unsigned short* __restrict__ u, const int* __restrict__ row_off,
    const int* __restrict__ col, const float* __restrict__ inv_s,
    unsigned short* __restrict__ out, int N) {
  constexpr int NSLICE = CH / 32;
  int wg = blockIdx.x;
  int slice = wg % NSLICE;
  int ng = wg / NSLICE;
  int wave = threadIdx.x >> 6;
  int lane = threadIdx.x & 63;
  int grp = lane >> 2;  // 16 node-groups per wave
  int c = lane & 3;     // 4 lanes x 16B = 64B slice
  int i = ng * 64 + wave * 16 + grp;
  bool valid = i < N;
  int e0 = 0, e1 = 0;
  if (valid) {
    e0 = row_off[i];
    e1 = row_off[i + 1];
  }
  unsigned cofs = slice * 64 + c * 16;  // byte offset within the CH*2-byte row
  const char* u8 = (const char*)u;
  float acc[8] = {};
  int e = e0;
  for (; e + 1 < e1; e += 2) {
    int j0 = col[e], j1 = col[e + 1];
    uint4 r0 = *(const uint4*)(u8 + (size_t)j0 * (CH * 2) + cofs);
    uint4 r1 = *(const uint4*)(u8 + (size_t)j1 * (CH * 2) + cofs);
    acc8(acc, r0);
    acc8(acc, r1);
  }
  if (e < e1) {
    int j = col[e];
    uint4 r = *(const uint4*)(u8 + (size_t)j * (CH * 2) + cofs);
    acc8(acc, r);
  }
  if (valid) {
    uint4 self = *(const uint4*)(u8 + (size_t)i * (CH * 2) + cofs);
    acc8(acc, self);
    float s = inv_s[i];
    uint4 o;
    o.x = pack2(s * acc[0], s * acc[1]);
    o.y = pack2(s * acc[2], s * acc[3]);
    o.z = pack2(s * acc[4], s * acc[5]);
    o.w = pack2(s * acc[6], s * acc[7]);
    *(uint4*)((char*)out + (size_t)i * (CH * 2) + cofs) = o;
  }
}

// ----------------------------- MFMA GEMM ------------------------------------
// C[M,256] = A[M,K] @ W[K,256] (+bias, opt relu)
// BM=128, 8 waves (2 row-halves x 4 col-quarters), 512 threads. (round-4 best)
// WRITE_U: out = bf16( inv_s[r] * (C + gh[batch[r]]) )   (next layer's u)
// else:    out = bf16( C )                               (final h)
template <int K, bool RELU, bool WRITE_U>
__global__ __launch_bounds__(512) void gemm_kernel(
    const unsigned short* __restrict__ A,   // [M][K] bf16
    const unsigned short* __restrict__ Bt,  // [256][K] bf16 (W transposed)
    const float* __restrict__ bias,         // [256]
    const float* __restrict__ inv_s, const int* __restrict__ batch,
    const float* __restrict__ gh,           // [G][256]
    unsigned short* __restrict__ out,       // [M][256] bf16
    int M) {
  constexpr int BK = 32;
  constexpr int LDT = 40;  // padded stride in ushorts: 80 B (16B-aligned, bank-friendly)
  __shared__ unsigned short As[128 * LDT];
  __shared__ unsigned short Bs[256 * LDT];
  int tid = threadIdx.x;
  int wave = tid >> 6, lane = tid & 63;
  int quad = lane >> 4, l15 = lane & 15;
  int wr = wave >> 2, wc = wave & 3;
  int row0 = blockIdx.x * 128;
  f32x4 acc[4][4];
#pragma unroll
  for (int m = 0; m < 4; ++m)
#pragma unroll
    for (int n = 0; n < 4; ++n) acc[m][n] = (f32x4){0.f, 0.f, 0.f, 0.f};

  for (int k0 = 0; k0 < K; k0 += BK) {
    {  // stage A: 128 rows x 32 k (one uint4 per thread)
      int r = tid >> 2, kq = tid & 3;
      int gr = row0 + r;
      uint4 v = make_uint4(0u, 0u, 0u, 0u);
      if (gr < M) v = *(const uint4*)&A[(size_t)gr * K + k0 + kq * 8];
      *(uint4*)&As[r * LDT + kq * 8] = v;
    }
#pragma unroll
    for (int p = 0; p < 2; ++p) {  // stage B: 256 rows x 32 k (two uint4 per thread)
      int n = (tid >> 2) + p * 128, kq = tid & 3;
      *(uint4*)&Bs[n * LDT + kq * 8] = *(const uint4*)&Bt[(size_t)n * K + k0 + kq * 8];
    }
    __syncthreads();
    bf16x8 af[4], bfr[4];
#pragma unroll
    for (int m = 0; m < 4; ++m)
      af[m] = __builtin_bit_cast(
          bf16x8, *(const uint4*)&As[(wr * 64 + m * 16 + l15) * LDT + quad * 8]);
#pragma unroll
    for (int n = 0; n < 4; ++n)
      bfr[n] = __builtin_bit_cast(
          bf16x8, *(const uint4*)&Bs[(wc * 64 + n * 16 + l15) * LDT + quad * 8]);
#pragma unroll
    for (int m = 0; m < 4; ++m)
#pragma unroll
      for (int n = 0; n < 4; ++n)
        acc[m][n] = __builtin_amdgcn_mfma_f32_16x16x32_bf16(af[m], bfr[n], acc[m][n], 0, 0, 0);
    __syncthreads();
  }
  // epilogue: C/D map col=lane&15, row=(lane>>4)*4+reg
#pragma unroll
  for (int m = 0; m < 4; ++m) {
#pragma unroll
    for (int r = 0; r < 4; ++r) {
      int gr = row0 + wr * 64 + m * 16 + quad * 4 + r;
      if (gr >= M) continue;
      float sv = 1.0f;
      int bofs = 0;
      if (WRITE_U) {
        sv = inv_s[gr];
        bofs = batch[gr] * 256;
      }
#pragma unroll
      for (int n = 0; n < 4; ++n) {
        int cc = wc * 64 + n * 16 + l15;
        float v = acc[m][n][r] + bias[cc];
        if (RELU) v = fmaxf(v, 0.f);
        if (WRITE_U) v = sv * (v + gh[bofs + cc]);
        out[(size_t)gr * 256 + cc] = f2bf(v);
      }
    }
  }
}

// ----------------------------- pool + final ---------------------------------

__global__ void pool_kernel(const unsigned short* __restrict__ h, const int* __restrict__ batch,
                            float* __restrict__ gmsum, float* __restrict__ cnt, int N, int chunk) {
  int start = blockIdx.x * chunk;
  int end = min(start + chunk, N);
  if (start >= end) return;
  int c = threadIdx.x;
  int g = batch[start];
  float acc = 0.0f;
  int run = 0;
  for (int n = start; n < end; ++n) {
    int bg = batch[n];
    if (bg != g) {
      atomicAdd(&gmsum[g * 256 + c], acc);
      if (c == 0) atomicAdd(&cnt[g], (float)run);
      acc = 0.0f;
      run = 0;
      g = bg;
    }
    acc += bf2f(h[(size_t)n * 256 + c]);
    run++;
  }
  atomicAdd(&gmsum[g * 256 + c], acc);
  if (c == 0) atomicAdd(&cnt[g], (float)run);
}

__global__ void final_kernel(const float* __restrict__ gmsum, const float* __restrict__ cnt,
                             const float* __restrict__ gh, const float* __restrict__ Wlin,
                             const float* __restrict__ blin, float* __restrict__ y,
                             float* __restrict__ gm_out, int G) {
  int g = blockIdx.x;
  int c = threadIdx.x;
  __shared__ float row[256];
  float v = gmsum[g * 256 + c] / fmaxf(cnt[g], 1.0f) + gh[g * 256 + c];
  gm_out[g * 256 + c] = v;
  row[c] = v;
  __syncthreads();
  if (c < 10) {
    float acc = blin[c];
    for (int k = 0; k < 256; ++k) acc += row[k] * Wlin[k * 10 + c];
    y[g * 10 + c] = acc;
  }
}

// ----------------------------- launch ----------------------------------------

extern "C" void kernel_launch(void* const* d_in, const int* in_sizes, int n_in,
                              void* d_out, int out_size, void* d_ws, size_t ws_size,
                              hipStream_t stream) {
  const float* x = (const float*)d_in[0];
  const int* ei = (const int*)d_in[1];
  const int* batch = (const int*)d_in[2];
  const float* gh = (const float*)d_in[3];
  const float* W0 = (const float*)d_in[4];
  const float* b0 = (const float*)d_in[5];
  const float* Ws = (const float*)d_in[6];
  const float* bs = (const float*)d_in[7];
  const float* Wlin = (const float*)d_in[8];
  const float* blin = (const float*)d_in[9];
  float* out = (float*)d_out;

  const int N = in_sizes[2];
  const int E = in_sizes[1] / 2;
  const int G = in_sizes[3] / 256;
  const int H = 256, L = 3, C = 10, F = 128;

  char* ws = (char*)d_ws;
  size_t off = 0;
  auto alloc = [&](size_t bytes) {
    void* p = ws + off;
    off += (bytes + 255) & ~(size_t)255;
    return p;
  };
  // NOTE: deg+cursor and cnt+gmsum are kept contiguous for merged memsets.
  size_t degspan = ((size_t)N * 4 + 255) & ~(size_t)255;
  size_t cntspan = ((size_t)G * 4 + 255) & ~(size_t)255;
  int* deg = (int*)alloc((size_t)N * 4);
  int* cursor = (int*)alloc((size_t)N * 4);
  float* cnt = (float*)alloc((size_t)G * 4);
  float* gmsum = (float*)alloc((size_t)G * H * 4);
  int* row_off = (int*)alloc((size_t)(N + 1) * 4);
  int* bsum = (int*)alloc(256 * 4);
  int* boff = (int*)alloc(256 * 4);
  int* col = (int*)alloc((size_t)E * 4);
  float* inv_s = (float*)alloc((size_t)N * 4);
  unsigned short* u_x = (unsigned short*)alloc((size_t)N * F * 2);   // s*x
  unsigned short* uA = (unsigned short*)alloc((size_t)N * H * 2);    // s*(h+res)
  unsigned short* aggA = (unsigned short*)alloc((size_t)N * H * 2);  // aggregate out / GEMM A
  unsigned short* hfin = (unsigned short*)alloc((size_t)N * H * 2);  // final h
  unsigned short* Wt0 = (unsigned short*)alloc((size_t)F * H * 2);   // [256][128]
  unsigned short* WtS = (unsigned short*)alloc((size_t)L * H * H * 2);

  const int* srcv = ei;
  const int* dstv = ei + E;

  hipMemsetAsync(deg, 0, degspan + (size_t)N * 4, stream);       // deg + cursor
  hipMemsetAsync(cnt, 0, cntspan + (size_t)G * H * 4, stream);   // cnt + gmsum

  int EB = (E + 255) / 256;
  int NB = (N + 255) / 256;
  count_deg_kernel<<<EB, 256, 0, stream>>>(dstv, deg, E);
  scan_partial_kernel<<<NB, 256, 0, stream>>>(deg, inv_s, bsum, N);
  scan_block_kernel<<<1, 256, 0, stream>>>(bsum, boff, row_off, NB, N);
  scan_final_kernel<<<NB, 256, 0, stream>>>(deg, boff, row_off, N);
  fill_csr_kernel<<<EB, 256, 0, stream>>>(srcv, dstv, row_off, cursor, col, E);

  prep_ux_kernel<<<(N * F + 255) / 256, 256, 0, stream>>>(x, inv_s, u_x, N * F);
  int TW = F * H + 3 * H * H;
  transpose_all_kernel<<<(TW + 255) / 256, 256, 0, stream>>>(W0, Ws, Wt0, WtS);

  int NGB = (N + 63) / 64;  // node groups of 64 (4 waves x 16)
  int GEMM_GRID = (N + 127) / 128;

  // layer 0: agg(u_x) -> GEMM K=128 (no relu) -> uA = s*(h0+res)
  aggregate_sliced_kernel<128><<<NGB * 4, 256, 0, stream>>>(u_x, row_off, col, inv_s, aggA, N);
  gemm_kernel<128, false, true><<<GEMM_GRID, 512, 0, stream>>>(aggA, Wt0, b0, inv_s, batch, gh,
                                                               uA, N);
  // layers 1..2: agg(uA) -> GEMM relu -> uA
  for (int l = 0; l < 2; ++l) {
    aggregate_sliced_kernel<256><<<NGB * 8, 256, 0, stream>>>(uA, row_off, col, inv_s, aggA, N);
    gemm_kernel<256, true, true><<<GEMM_GRID, 512, 0, stream>>>(
        aggA, WtS + (size_t)l * H * H, bs + (size_t)l * H, inv_s, batch, gh, uA, N);
  }
  // layer 3: agg(uA) -> GEMM relu -> h (bf16)
  aggregate_sliced_kernel<256><<<NGB * 8, 256, 0, stream>>>(uA, row_off, col, inv_s, aggA, N);
  gemm_kernel<256, true, false><<<GEMM_GRID, 512, 0, stream>>>(
      aggA, WtS + (size_t)2 * H * H, bs + (size_t)2 * H, inv_s, batch, gh, hfin, N);

  int PB = 1024;
  int chunk = (N + PB - 1) / PB;
  pool_kernel<<<PB, 256, 0, stream>>>(hfin, batch, gmsum, cnt, N, chunk);
  final_kernel<<<G, 256, 0, stream>>>(gmsum, cnt, gh, Wlin, blin, out, out + (size_t)G * C, G);
}

// Round 7
// 433.512 us; speedup vs baseline: 1.4021x; 1.4021x over previous
//
#include <hip/hip_runtime.h>

// ---------------------------------------------------------------------------
// BlockGNN on MI355X, round 9:
//   - gather array u stored as fp8 e4m3 (OCP, HW cvt on gfx950). Agg is
//     HBM-transaction-bound on 8x-duplicated L2 misses (r4-r8: 186MB fetch vs
//     25.6MB ws, 3.2TB/s plateau across 3 structures; XCD-slicing made it
//     WORSE, 254MB). Only lever left: halve the bytes. f32 accumulation;
//     aggA/GEMM stay bf16; outputs are graph-pooled so per-node quant noise
//     averages down ~1/70.
//   - aggregate: round-4 skeleton (clamped 4-deep batch, compiler-scheduled;
//     depth proven not the limiter).
//   - GEMM: round-4 LDS BM=128/512thr; WRITE_U epilogue emits fp8 u.
// ---------------------------------------------------------------------------

typedef __bf16 bf16x8 __attribute__((ext_vector_type(8)));
typedef float f32x4 __attribute__((ext_vector_type(4)));
typedef float f32x2 __attribute__((ext_vector_type(2)));

__device__ inline float bf2f(unsigned short u) {
  union { unsigned int i; float f; } v;
  v.i = (unsigned int)u << 16;
  return v.f;
}
__device__ inline unsigned short f2bf(float f) {
  union { unsigned int i; float f; } v;
  v.f = f;
  unsigned int i = v.i;
  return (unsigned short)((i + 0x7fffu + ((i >> 16) & 1u)) >> 16);  // RNE
}
__device__ inline unsigned int pack2(float a, float b) {
  return (unsigned int)f2bf(a) | ((unsigned int)f2bf(b) << 16);
}
__device__ inline void acc8(float* acc, uint4 r) {
  unsigned int w[4] = {r.x, r.y, r.z, r.w};
#pragma unroll
  for (int q = 0; q < 4; ++q) {
    acc[2 * q] += bf2f((unsigned short)(w[q] & 0xffffu));
    acc[2 * q + 1] += bf2f((unsigned short)(w[q] >> 16));
  }
}
// fp8 e4m3 pack of 4 floats -> dword (bytes 0..3)
__device__ inline unsigned pack4_fp8(float a, float b, float c, float d) {
  int r = 0;
  r = __builtin_amdgcn_cvt_pk_fp8_f32(a, b, r, false);
  r = __builtin_amdgcn_cvt_pk_fp8_f32(c, d, r, true);
  return (unsigned)r;
}
// accumulate 16 fp8 channels (one uint4) into acc[16]; msk==0 squashes (+0.0)
__device__ inline void acc16_fp8(float* acc, uint4 r, unsigned msk) {
  unsigned w[4] = {r.x, r.y, r.z, r.w};
#pragma unroll
  for (int d = 0; d < 4; ++d) {
    int v = (int)(w[d] & msk);
    f32x2 lo = __builtin_amdgcn_cvt_pk_f32_fp8(v, false);
    f32x2 hi = __builtin_amdgcn_cvt_pk_f32_fp8(v, true);
    acc[4 * d + 0] += lo[0];
    acc[4 * d + 1] += lo[1];
    acc[4 * d + 2] += hi[0];
    acc[4 * d + 3] += hi[1];
  }
}

// ----------------------------- CSR build -----------------------------------

__global__ void count_deg_kernel(const int* __restrict__ dst, int* __restrict__ deg, int E) {
  int e = blockIdx.x * blockDim.x + threadIdx.x;
  if (e < E) atomicAdd(&deg[dst[e]], 1);
}

// fused: per-block degree sums for the scan + inv_s = rsqrt(deg+1)
__global__ void scan_partial_kernel(const int* __restrict__ deg, float* __restrict__ inv_s,
                                    int* __restrict__ bsum, int N) {
  __shared__ int s[256];
  int i = blockIdx.x * 256 + threadIdx.x;
  int d = (i < N) ? deg[i] : 0;
  if (i < N) inv_s[i] = rsqrtf((float)(d + 1));  // +1 self loop
  s[threadIdx.x] = d;
  __syncthreads();
  for (int off = 128; off > 0; off >>= 1) {
    if (threadIdx.x < off) s[threadIdx.x] += s[threadIdx.x + off];
    __syncthreads();
  }
  if (threadIdx.x == 0) bsum[blockIdx.x] = s[0];
}

__global__ void scan_block_kernel(const int* __restrict__ bsum, int* __restrict__ boff,
                                  int* __restrict__ row_off, int NB, int N) {
  __shared__ int s[256];
  int v = (threadIdx.x < NB) ? bsum[threadIdx.x] : 0;
  s[threadIdx.x] = v;
  __syncthreads();
  for (int off = 1; off < 256; off <<= 1) {
    int t = (threadIdx.x >= off) ? s[threadIdx.x - off] : 0;
    __syncthreads();
    s[threadIdx.x] += t;
    __syncthreads();
  }
  boff[threadIdx.x] = s[threadIdx.x] - v;
  if (threadIdx.x == 255) row_off[N] = s[255];
}

__global__ void scan_final_kernel(const int* __restrict__ deg, const int* __restrict__ boff,
                                  int* __restrict__ row_off, int N) {
  __shared__ int s[256];
  int i = blockIdx.x * 256 + threadIdx.x;
  int v = (i < N) ? deg[i] : 0;
  s[threadIdx.x] = v;
  __syncthreads();
  for (int off = 1; off < 256; off <<= 1) {
    int t = (threadIdx.x >= off) ? s[threadIdx.x - off] : 0;
    __syncthreads();
    s[threadIdx.x] += t;
    __syncthreads();
  }
  if (i < N) row_off[i] = boff[blockIdx.x] + s[threadIdx.x] - v;
}

__global__ void fill_csr_kernel(const int* __restrict__ src, const int* __restrict__ dst,
                                const int* __restrict__ row_off, int* __restrict__ cursor,
                                int* __restrict__ col, int E) {
  int e = blockIdx.x * blockDim.x + threadIdx.x;
  if (e < E) {
    int d = dst[e];
    int pos = atomicAdd(&cursor[d], 1);
    col[row_off[d] + pos] = src[e];
  }
}

// ----------------------------- prep ----------------------------------------

// u_x fp8: u[i][c] = fp8( inv_s[i] * x[i][c] ), CH=128 -> N*32 dwords
__global__ void prep_ux_fp8_kernel(const float* __restrict__ x, const float* __restrict__ inv_s,
                                   unsigned* __restrict__ u, int total_dw) {
  int idx = blockIdx.x * 256 + threadIdx.x;
  if (idx < total_dw) {
    int i = idx >> 5;  // node (32 dwords per 128-ch row)
    float s = inv_s[i];
    float4 v = *(const float4*)&x[(size_t)idx * 4];
    u[idx] = pack4_fp8(s * v.x, s * v.y, s * v.z, s * v.w);
  }
}

// single kernel transposing W0 [128][256] and 3x Ws [256][256] to bf16
__global__ void transpose_all_kernel(const float* __restrict__ W0, const float* __restrict__ Ws,
                                     unsigned short* __restrict__ Wt0,
                                     unsigned short* __restrict__ WtS) {
  const int FH = 128 * 256, HH = 256 * 256;
  int idx = blockIdx.x * 256 + threadIdx.x;
  if (idx < FH) {
    int k = idx >> 8, n = idx & 255;
    Wt0[n * 128 + k] = f2bf(W0[idx]);
  } else {
    int t = idx - FH;
    if (t < 3 * HH) {
      int l = t >> 16;
      int rem = t & 65535;
      int k = rem >> 8, n = rem & 255;
      WtS[l * HH + n * 256 + k] = f2bf(Ws[t]);
    }
  }
}

// ----------------------------- aggregate (fp8 gather) ------------------------
// out_i = bf16( s_i * ( u_i + sum_j u_j ) ), u stored fp8 e4m3 [N][CH] (CH B/row).
// One wave per node; LPR lanes x 16B (16 fp8 ch) per row; EPW edge-groups/wave;
// clamped 4-deep batch (64B/lane in flight), AND-mask squash (fp8 0x00 = +0).
template <int CH>
__global__ __launch_bounds__(256) void aggregate_fp8_kernel(
    const unsigned char* __restrict__ u, const int* __restrict__ row_off,
    const int* __restrict__ col, const float* __restrict__ inv_s,
    unsigned short* __restrict__ out, int N) {
  constexpr int LPR = CH / 16;   // lanes per row (16 fp8 = 16B per lane)
  constexpr int EPW = 64 / LPR;  // edge-groups in parallel per wave
  int wave = threadIdx.x >> 6;
  int lane = threadIdx.x & 63;
  int i = blockIdx.x * 4 + wave;
  if (i >= N) return;
  int sub = lane / LPR;
  int c = lane % LPR;
  int e0 = row_off[i], e1 = row_off[i + 1];
  int last = e1 - 1;
  float acc[16] = {};
  for (int e = e0 + sub; e < e1; e += 4 * EPW) {
    unsigned off[4];
    unsigned msk[4];
#pragma unroll
    for (int q = 0; q < 4; ++q) {
      int ee = e + q * EPW;
      bool v = ee < e1;
      int j = col[v ? ee : last];
      off[q] = (unsigned)j * CH + c * 16;
      msk[q] = v ? 0xffffffffu : 0u;
    }
    uint4 r[4];
#pragma unroll
    for (int q = 0; q < 4; ++q) r[q] = *(const uint4*)(u + off[q]);
#pragma unroll
    for (int q = 0; q < 4; ++q) acc16_fp8(acc, r[q], msk[q]);
  }
#pragma unroll
  for (int o = 32; o >= LPR; o >>= 1)
#pragma unroll
    for (int k = 0; k < 16; ++k) acc[k] += __shfl_down(acc[k], o);
  if (lane < LPR) {
    uint4 self = *(const uint4*)(u + (size_t)i * CH + c * 16);
    acc16_fp8(acc, self, 0xffffffffu);
    float s = inv_s[i];
    uint4 o1, o2;
    o1.x = pack2(s * acc[0], s * acc[1]);
    o1.y = pack2(s * acc[2], s * acc[3]);
    o1.z = pack2(s * acc[4], s * acc[5]);
    o1.w = pack2(s * acc[6], s * acc[7]);
    o2.x = pack2(s * acc[8], s * acc[9]);
    o2.y = pack2(s * acc[10], s * acc[11]);
    o2.z = pack2(s * acc[12], s * acc[13]);
    o2.w = pack2(s * acc[14], s * acc[15]);
    *(uint4*)&out[(size_t)i * CH + c * 16] = o1;
    *(uint4*)&out[(size_t)i * CH + c * 16 + 8] = o2;
  }
}

// ----------------------------- MFMA GEMM ------------------------------------
// C[M,256] = A[M,K] @ W[K,256] (+bias, opt relu)
// BM=128, 8 waves (2 row-halves x 4 col-quarters), 512 threads. (round-4 best)
// WRITE_U: out = fp8( inv_s[r] * (C + gh[batch[r]]) )    (next layer's u, fp8)
// else:    out = bf16( C )                                (final h, bf16)
template <int K, bool RELU, bool WRITE_U>
__global__ __launch_bounds__(512) void gemm_kernel(
    const unsigned short* __restrict__ A,   // [M][K] bf16
    const unsigned short* __restrict__ Bt,  // [256][K] bf16 (W transposed)
    const float* __restrict__ bias,         // [256]
    const float* __restrict__ inv_s, const int* __restrict__ batch,
    const float* __restrict__ gh,           // [G][256]
    void* __restrict__ outp,                // fp8 [M][256] or bf16 [M][256]
    int M) {
  constexpr int BK = 32;
  constexpr int LDT = 40;  // padded stride in ushorts: 80 B (16B-aligned, bank-friendly)
  __shared__ unsigned short As[128 * LDT];
  __shared__ unsigned short Bs[256 * LDT];
  int tid = threadIdx.x;
  int wave = tid >> 6, lane = tid & 63;
  int quad = lane >> 4, l15 = lane & 15;
  int wr = wave >> 2, wc = wave & 3;
  int row0 = blockIdx.x * 128;
  f32x4 acc[4][4];
#pragma unroll
  for (int m = 0; m < 4; ++m)
#pragma unroll
    for (int n = 0; n < 4; ++n) acc[m][n] = (f32x4){0.f, 0.f, 0.f, 0.f};

  for (int k0 = 0; k0 < K; k0 += BK) {
    {  // stage A: 128 rows x 32 k (one uint4 per thread)
      int r = tid >> 2, kq = tid & 3;
      int gr = row0 + r;
      uint4 v = make_uint4(0u, 0u, 0u, 0u);
      if (gr < M) v = *(const uint4*)&A[(size_t)gr * K + k0 + kq * 8];
      *(uint4*)&As[r * LDT + kq * 8] = v;
    }
#pragma unroll
    for (int p = 0; p < 2; ++p) {  // stage B: 256 rows x 32 k (two uint4 per thread)
      int n = (tid >> 2) + p * 128, kq = tid & 3;
      *(uint4*)&Bs[n * LDT + kq * 8] = *(const uint4*)&Bt[(size_t)n * K + k0 + kq * 8];
    }
    __syncthreads();
    bf16x8 af[4], bfr[4];
#pragma unroll
    for (int m = 0; m < 4; ++m)
      af[m] = __builtin_bit_cast(
          bf16x8, *(const uint4*)&As[(wr * 64 + m * 16 + l15) * LDT + quad * 8]);
#pragma unroll
    for (int n = 0; n < 4; ++n)
      bfr[n] = __builtin_bit_cast(
          bf16x8, *(const uint4*)&Bs[(wc * 64 + n * 16 + l15) * LDT + quad * 8]);
#pragma unroll
    for (int m = 0; m < 4; ++m)
#pragma unroll
      for (int n = 0; n < 4; ++n)
        acc[m][n] = __builtin_amdgcn_mfma_f32_16x16x32_bf16(af[m], bfr[n], acc[m][n], 0, 0, 0);
    __syncthreads();
  }
  // epilogue: C/D map col=lane&15, row=(lane>>4)*4+reg
#pragma unroll
  for (int m = 0; m < 4; ++m) {
#pragma unroll
    for (int r = 0; r < 4; ++r) {
      int gr = row0 + wr * 64 + m * 16 + quad * 4 + r;
      if (gr >= M) continue;
      float sv = 1.0f;
      int bofs = 0;
      if (WRITE_U) {
        sv = inv_s[gr];
        bofs = batch[gr] * 256;
      }
#pragma unroll
      for (int n = 0; n < 4; ++n) {
        int cc = wc * 64 + n * 16 + l15;
        float v = acc[m][n][r] + bias[cc];
        if (RELU) v = fmaxf(v, 0.f);
        if (WRITE_U) {
          v = sv * (v + gh[bofs + cc]);
          unsigned pr = (unsigned)__builtin_amdgcn_cvt_pk_fp8_f32(v, v, 0, false);
          ((unsigned char*)outp)[(size_t)gr * 256 + cc] = (unsigned char)(pr & 0xffu);
        } else {
          ((unsigned short*)outp)[(size_t)gr * 256 + cc] = f2bf(v);
        }
      }
    }
  }
}

// ----------------------------- pool + final ---------------------------------

__global__ void pool_kernel(const unsigned short* __restrict__ h, const int* __restrict__ batch,
                            float* __restrict__ gmsum, float* __restrict__ cnt, int N, int chunk) {
  int start = blockIdx.x * chunk;
  int end = min(start + chunk, N);
  if (start >= end) return;
  int c = threadIdx.x;
  int g = batch[start];
  float acc = 0.0f;
  int run = 0;
  for (int n = start; n < end; ++n) {
    int bg = batch[n];
    if (bg != g) {
      atomicAdd(&gmsum[g * 256 + c], acc);
      if (c == 0) atomicAdd(&cnt[g], (float)run);
      acc = 0.0f;
      run = 0;
      g = bg;
    }
    acc += bf2f(h[(size_t)n * 256 + c]);
    run++;
  }
  atomicAdd(&gmsum[g * 256 + c], acc);
  if (c == 0) atomicAdd(&cnt[g], (float)run);
}

__global__ void final_kernel(const float* __restrict__ gmsum, const float* __restrict__ cnt,
                             const float* __restrict__ gh, const float* __restrict__ Wlin,
                             const float* __restrict__ blin, float* __restrict__ y,
                             float* __restrict__ gm_out, int G) {
  int g = blockIdx.x;
  int c = threadIdx.x;
  __shared__ float row[256];
  float v = gmsum[g * 256 + c] / fmaxf(cnt[g], 1.0f) + gh[g * 256 + c];
  gm_out[g * 256 + c] = v;
  row[c] = v;
  __syncthreads();
  if (c < 10) {
    float acc = blin[c];
    for (int k = 0; k < 256; ++k) acc += row[k] * Wlin[k * 10 + c];
    y[g * 10 + c] = acc;
  }
}

// ----------------------------- launch ----------------------------------------

extern "C" void kernel_launch(void* const* d_in, const int* in_sizes, int n_in,
                              void* d_out, int out_size, void* d_ws, size_t ws_size,
                              hipStream_t stream) {
  const float* x = (const float*)d_in[0];
  const int* ei = (const int*)d_in[1];
  const int* batch = (const int*)d_in[2];
  const float* gh = (const float*)d_in[3];
  const float* W0 = (const float*)d_in[4];
  const float* b0 = (const float*)d_in[5];
  const float* Ws = (const float*)d_in[6];
  const float* bs = (const float*)d_in[7];
  const float* Wlin = (const float*)d_in[8];
  const float* blin = (const float*)d_in[9];
  float* out = (float*)d_out;

  const int N = in_sizes[2];
  const int E = in_sizes[1] / 2;
  const int G = in_sizes[3] / 256;
  const int H = 256, L = 3, C = 10, F = 128;

  char* ws = (char*)d_ws;
  size_t off = 0;
  auto alloc = [&](size_t bytes) {
    void* p = ws + off;
    off += (bytes + 255) & ~(size_t)255;
    return p;
  };
  // NOTE: deg+cursor and cnt+gmsum are kept contiguous for merged memsets.
  size_t degspan = ((size_t)N * 4 + 255) & ~(size_t)255;
  size_t cntspan = ((size_t)G * 4 + 255) & ~(size_t)255;
  int* deg = (int*)alloc((size_t)N * 4);
  int* cursor = (int*)alloc((size_t)N * 4);
  float* cnt = (float*)alloc((size_t)G * 4);
  float* gmsum = (float*)alloc((size_t)G * H * 4);
  int* row_off = (int*)alloc((size_t)(N + 1) * 4);
  int* bsum = (int*)alloc(256 * 4);
  int* boff = (int*)alloc(256 * 4);
  int* col = (int*)alloc((size_t)E * 4);
  float* inv_s = (float*)alloc((size_t)N * 4);
  unsigned char* u_x = (unsigned char*)alloc((size_t)N * F);        // fp8 s*x
  unsigned char* uA = (unsigned char*)alloc((size_t)N * H);        // fp8 s*(h+res)
  unsigned short* aggA = (unsigned short*)alloc((size_t)N * H * 2);  // bf16 agg out / GEMM A
  unsigned short* hfin = (unsigned short*)alloc((size_t)N * H * 2);  // final h bf16
  unsigned short* Wt0 = (unsigned short*)alloc((size_t)F * H * 2);   // [256][128]
  unsigned short* WtS = (unsigned short*)alloc((size_t)L * H * H * 2);

  const int* srcv = ei;
  const int* dstv = ei + E;

  hipMemsetAsync(deg, 0, degspan + (size_t)N * 4, stream);       // deg + cursor
  hipMemsetAsync(cnt, 0, cntspan + (size_t)G * H * 4, stream);   // cnt + gmsum

  int EB = (E + 255) / 256;
  int NB = (N + 255) / 256;
  count_deg_kernel<<<EB, 256, 0, stream>>>(dstv, deg, E);
  scan_partial_kernel<<<NB, 256, 0, stream>>>(deg, inv_s, bsum, N);
  scan_block_kernel<<<1, 256, 0, stream>>>(bsum, boff, row_off, NB, N);
  scan_final_kernel<<<NB, 256, 0, stream>>>(deg, boff, row_off, N);
  fill_csr_kernel<<<EB, 256, 0, stream>>>(srcv, dstv, row_off, cursor, col, E);

  int UXDW = N * (F / 4);
  prep_ux_fp8_kernel<<<(UXDW + 255) / 256, 256, 0, stream>>>(x, inv_s, (unsigned*)u_x, UXDW);
  int TW = F * H + 3 * H * H;
  transpose_all_kernel<<<(TW + 255) / 256, 256, 0, stream>>>(W0, Ws, Wt0, WtS);

  int AGG_GRID = (N + 3) / 4;
  int GEMM_GRID = (N + 127) / 128;

  // layer 0: agg(u_x fp8) -> GEMM K=128 (no relu) -> uA = fp8(s*(h0+res))
  aggregate_fp8_kernel<128><<<AGG_GRID, 256, 0, stream>>>(u_x, row_off, col, inv_s, aggA, N);
  gemm_kernel<128, false, true><<<GEMM_GRID, 512, 0, stream>>>(aggA, Wt0, b0, inv_s, batch, gh,
                                                               uA, N);
  // layers 1..2: agg(uA fp8) -> GEMM relu -> uA fp8
  for (int l = 0; l < 2; ++l) {
    aggregate_fp8_kernel<256><<<AGG_GRID, 256, 0, stream>>>(uA, row_off, col, inv_s, aggA, N);
    gemm_kernel<256, true, true><<<GEMM_GRID, 512, 0, stream>>>(
        aggA, WtS + (size_t)l * H * H, bs + (size_t)l * H, inv_s, batch, gh, uA, N);
  }
  // layer 3: agg(uA fp8) -> GEMM relu -> h (bf16)
  aggregate_fp8_kernel<256><<<AGG_GRID, 256, 0, stream>>>(uA, row_off, col, inv_s, aggA, N);
  gemm_kernel<256, true, false><<<GEMM_GRID, 512, 0, stream>>>(
      aggA, WtS + (size_t)2 * H * H, bs + (size_t)2 * H, inv_s, batch, gh, hfin, N);

  int PB = 1024;
  int chunk = (N + PB - 1) / PB;
  pool_kernel<<<PB, 256, 0, stream>>>(hfin, batch, gmsum, cnt, N, chunk);
  final_kernel<<<G, 256, 0, stream>>>(gmsum, cnt, gh, Wlin, blin, out, out + (size_t)G * C, G);
}

// Round 8
// 395.844 us; speedup vs baseline: 1.5356x; 1.0952x over previous
//
#include <hip/hip_runtime.h>

// ---------------------------------------------------------------------------
// BlockGNN on MI355X, round 10:
//   - CSR build: pos recorded during the counting pass (atomicAdd return),
//     fill pass is a pure no-atomic scatter (4 edges/thread, int4 loads).
//     Round-9 fill_csr was 51us = atomic serialization + 64B-line write
//     amplification; this removes the atomics half.
//   - fp8 gather pipeline unchanged (r9: -78us, absmax unchanged).
//   - prep_ux + transpose merged into one kernel; cursor buffer gone.
// ---------------------------------------------------------------------------

typedef __bf16 bf16x8 __attribute__((ext_vector_type(8)));
typedef float f32x4 __attribute__((ext_vector_type(4)));
typedef float f32x2 __attribute__((ext_vector_type(2)));

__device__ inline float bf2f(unsigned short u) {
  union { unsigned int i; float f; } v;
  v.i = (unsigned int)u << 16;
  return v.f;
}
__device__ inline unsigned short f2bf(float f) {
  union { unsigned int i; float f; } v;
  v.f = f;
  unsigned int i = v.i;
  return (unsigned short)((i + 0x7fffu + ((i >> 16) & 1u)) >> 16);  // RNE
}
__device__ inline unsigned int pack2(float a, float b) {
  return (unsigned int)f2bf(a) | ((unsigned int)f2bf(b) << 16);
}
__device__ inline void acc8(float* acc, uint4 r) {
  unsigned int w[4] = {r.x, r.y, r.z, r.w};
#pragma unroll
  for (int q = 0; q < 4; ++q) {
    acc[2 * q] += bf2f((unsigned short)(w[q] & 0xffffu));
    acc[2 * q + 1] += bf2f((unsigned short)(w[q] >> 16));
  }
}
// fp8 e4m3 pack of 4 floats -> dword (bytes 0..3)
__device__ inline unsigned pack4_fp8(float a, float b, float c, float d) {
  int r = 0;
  r = __builtin_amdgcn_cvt_pk_fp8_f32(a, b, r, false);
  r = __builtin_amdgcn_cvt_pk_fp8_f32(c, d, r, true);
  return (unsigned)r;
}
// accumulate 16 fp8 channels (one uint4) into acc[16]; msk==0 squashes (+0.0)
__device__ inline void acc16_fp8(float* acc, uint4 r, unsigned msk) {
  unsigned w[4] = {r.x, r.y, r.z, r.w};
#pragma unroll
  for (int d = 0; d < 4; ++d) {
    int v = (int)(w[d] & msk);
    f32x2 lo = __builtin_amdgcn_cvt_pk_f32_fp8(v, false);
    f32x2 hi = __builtin_amdgcn_cvt_pk_f32_fp8(v, true);
    acc[4 * d + 0] += lo[0];
    acc[4 * d + 1] += lo[1];
    acc[4 * d + 2] += hi[0];
    acc[4 * d + 3] += hi[1];
  }
}

// ----------------------------- CSR build -----------------------------------

// counting pass that also records each edge's slot (atomicAdd return value).
// deg <= ~50 for this graph (Poisson mean 16), so u16 pos is safe.
__global__ void count_pos_kernel(const int* __restrict__ dst, int* __restrict__ deg,
                                 unsigned short* __restrict__ pos, int E) {
  int e = blockIdx.x * blockDim.x + threadIdx.x;
  if (e < E) pos[e] = (unsigned short)atomicAdd(&deg[dst[e]], 1);
}

// fused: per-block degree sums for the scan + inv_s = rsqrt(deg+1)
__global__ void scan_partial_kernel(const int* __restrict__ deg, float* __restrict__ inv_s,
                                    int* __restrict__ bsum, int N) {
  __shared__ int s[256];
  int i = blockIdx.x * 256 + threadIdx.x;
  int d = (i < N) ? deg[i] : 0;
  if (i < N) inv_s[i] = rsqrtf((float)(d + 1));  // +1 self loop
  s[threadIdx.x] = d;
  __syncthreads();
  for (int off = 128; off > 0; off >>= 1) {
    if (threadIdx.x < off) s[threadIdx.x] += s[threadIdx.x + off];
    __syncthreads();
  }
  if (threadIdx.x == 0) bsum[blockIdx.x] = s[0];
}

__global__ void scan_block_kernel(const int* __restrict__ bsum, int* __restrict__ boff,
                                  int* __restrict__ row_off, int NB, int N) {
  __shared__ int s[256];
  int v = (threadIdx.x < NB) ? bsum[threadIdx.x] : 0;
  s[threadIdx.x] = v;
  __syncthreads();
  for (int off = 1; off < 256; off <<= 1) {
    int t = (threadIdx.x >= off) ? s[threadIdx.x - off] : 0;
    __syncthreads();
    s[threadIdx.x] += t;
    __syncthreads();
  }
  boff[threadIdx.x] = s[threadIdx.x] - v;
  if (threadIdx.x == 255) row_off[N] = s[255];
}

__global__ void scan_final_kernel(const int* __restrict__ deg, const int* __restrict__ boff,
                                  int* __restrict__ row_off, int N) {
  __shared__ int s[256];
  int i = blockIdx.x * 256 + threadIdx.x;
  int v = (i < N) ? deg[i] : 0;
  s[threadIdx.x] = v;
  __syncthreads();
  for (int off = 1; off < 256; off <<= 1) {
    int t = (threadIdx.x >= off) ? s[threadIdx.x - off] : 0;
    __syncthreads();
    s[threadIdx.x] += t;
    __syncthreads();
  }
  if (i < N) row_off[i] = boff[blockIdx.x] + s[threadIdx.x] - v;
}

// pure scatter, no atomics: col[row_off[dst] + pos] = src. 4 edges/thread.
__global__ void fill_csr2_kernel(const int* __restrict__ src, const int* __restrict__ dst,
                                 const unsigned short* __restrict__ pos,
                                 const int* __restrict__ row_off, int* __restrict__ col, int E) {
  int t = blockIdx.x * blockDim.x + threadIdx.x;
  int e = t * 4;
  if (e + 3 < E) {
    int4 s4 = *(const int4*)&src[e];
    int4 d4 = *(const int4*)&dst[e];
    ushort4 p4 = *(const ushort4*)&pos[e];
    col[row_off[d4.x] + p4.x] = s4.x;
    col[row_off[d4.y] + p4.y] = s4.y;
    col[row_off[d4.z] + p4.z] = s4.z;
    col[row_off[d4.w] + p4.w] = s4.w;
  } else {
    for (; e < E; ++e) col[row_off[dst[e]] + pos[e]] = src[e];
  }
}

// ----------------------------- prep (merged) --------------------------------
// part 1: u_x fp8 dwords: u[i][c..c+3] = fp8(inv_s[i]*x[...]), N*32 dwords
// part 2: transpose W0 [128][256] and 3x Ws [256][256] to bf16
__global__ void prep_all_kernel(const float* __restrict__ x, const float* __restrict__ inv_s,
                                unsigned* __restrict__ u, int total_dw,
                                const float* __restrict__ W0, const float* __restrict__ Ws,
                                unsigned short* __restrict__ Wt0,
                                unsigned short* __restrict__ WtS) {
  const int FH = 128 * 256, HH = 256 * 256;
  int idx = blockIdx.x * 256 + threadIdx.x;
  if (idx < total_dw) {
    int i = idx >> 5;  // node (32 dwords per 128-ch row)
    float s = inv_s[i];
    float4 v = *(const float4*)&x[(size_t)idx * 4];
    u[idx] = pack4_fp8(s * v.x, s * v.y, s * v.z, s * v.w);
  } else {
    int w = idx - total_dw;
    if (w < FH) {
      int k = w >> 8, n = w & 255;
      Wt0[n * 128 + k] = f2bf(W0[w]);
    } else {
      int t = w - FH;
      if (t < 3 * HH) {
        int l = t >> 16;
        int rem = t & 65535;
        int k = rem >> 8, n = rem & 255;
        WtS[l * HH + n * 256 + k] = f2bf(Ws[t]);
      }
    }
  }
}

// ----------------------------- aggregate (fp8 gather) ------------------------
// out_i = bf16( s_i * ( u_i + sum_j u_j ) ), u stored fp8 e4m3 [N][CH] (CH B/row).
// One wave per node; LPR lanes x 16B (16 fp8 ch) per row; EPW edge-groups/wave;
// clamped 4-deep batch (64B/lane in flight), AND-mask squash (fp8 0x00 = +0).
template <int CH>
__global__ __launch_bounds__(256) void aggregate_fp8_kernel(
    const unsigned char* __restrict__ u, const int* __restrict__ row_off,
    const int* __restrict__ col, const float* __restrict__ inv_s,
    unsigned short* __restrict__ out, int N) {
  constexpr int LPR = CH / 16;   // lanes per row (16 fp8 = 16B per lane)
  constexpr int EPW = 64 / LPR;  // edge-groups in parallel per wave
  int wave = threadIdx.x >> 6;
  int lane = threadIdx.x & 63;
  int i = blockIdx.x * 4 + wave;
  if (i >= N) return;
  int sub = lane / LPR;
  int c = lane % LPR;
  int e0 = row_off[i], e1 = row_off[i + 1];
  int last = e1 - 1;
  float acc[16] = {};
  for (int e = e0 + sub; e < e1; e += 4 * EPW) {
    unsigned off[4];
    unsigned msk[4];
#pragma unroll
    for (int q = 0; q < 4; ++q) {
      int ee = e + q * EPW;
      bool v = ee < e1;
      int j = col[v ? ee : last];
      off[q] = (unsigned)j * CH + c * 16;
      msk[q] = v ? 0xffffffffu : 0u;
    }
    uint4 r[4];
#pragma unroll
    for (int q = 0; q < 4; ++q) r[q] = *(const uint4*)(u + off[q]);
#pragma unroll
    for (int q = 0; q < 4; ++q) acc16_fp8(acc, r[q], msk[q]);
  }
#pragma unroll
  for (int o = 32; o >= LPR; o >>= 1)
#pragma unroll
    for (int k = 0; k < 16; ++k) acc[k] += __shfl_down(acc[k], o);
  if (lane < LPR) {
    uint4 self = *(const uint4*)(u + (size_t)i * CH + c * 16);
    acc16_fp8(acc, self, 0xffffffffu);
    float s = inv_s[i];
    uint4 o1, o2;
    o1.x = pack2(s * acc[0], s * acc[1]);
    o1.y = pack2(s * acc[2], s * acc[3]);
    o1.z = pack2(s * acc[4], s * acc[5]);
    o1.w = pack2(s * acc[6], s * acc[7]);
    o2.x = pack2(s * acc[8], s * acc[9]);
    o2.y = pack2(s * acc[10], s * acc[11]);
    o2.z = pack2(s * acc[12], s * acc[13]);
    o2.w = pack2(s * acc[14], s * acc[15]);
    *(uint4*)&out[(size_t)i * CH + c * 16] = o1;
    *(uint4*)&out[(size_t)i * CH + c * 16 + 8] = o2;
  }
}

// ----------------------------- MFMA GEMM ------------------------------------
// C[M,256] = A[M,K] @ W[K,256] (+bias, opt relu)
// BM=128, 8 waves (2 row-halves x 4 col-quarters), 512 threads.
// WRITE_U: out = fp8( inv_s[r] * (C + gh[batch[r]]) )    (next layer's u, fp8)
// else:    out = bf16( C )                                (final h, bf16)
template <int K, bool RELU, bool WRITE_U>
__global__ __launch_bounds__(512) void gemm_kernel(
    const unsigned short* __restrict__ A,   // [M][K] bf16
    const unsigned short* __restrict__ Bt,  // [256][K] bf16 (W transposed)
    const float* __restrict__ bias,         // [256]
    const float* __restrict__ inv_s, const int* __restrict__ batch,
    const float* __restrict__ gh,           // [G][256]
    void* __restrict__ outp,                // fp8 [M][256] or bf16 [M][256]
    int M) {
  constexpr int BK = 32;
  constexpr int LDT = 40;  // padded stride in ushorts: 80 B (16B-aligned, bank-friendly)
  __shared__ unsigned short As[128 * LDT];
  __shared__ unsigned short Bs[256 * LDT];
  int tid = threadIdx.x;
  int wave = tid >> 6, lane = tid & 63;
  int quad = lane >> 4, l15 = lane & 15;
  int wr = wave >> 2, wc = wave & 3;
  int row0 = blockIdx.x * 128;
  f32x4 acc[4][4];
#pragma unroll
  for (int m = 0; m < 4; ++m)
#pragma unroll
    for (int n = 0; n < 4; ++n) acc[m][n] = (f32x4){0.f, 0.f, 0.f, 0.f};

  for (int k0 = 0; k0 < K; k0 += BK) {
    {  // stage A: 128 rows x 32 k (one uint4 per thread)
      int r = tid >> 2, kq = tid & 3;
      int gr = row0 + r;
      uint4 v = make_uint4(0u, 0u, 0u, 0u);
      if (gr < M) v = *(const uint4*)&A[(size_t)gr * K + k0 + kq * 8];
      *(uint4*)&As[r * LDT + kq * 8] = v;
    }
#pragma unroll
    for (int p = 0; p < 2; ++p) {  // stage B: 256 rows x 32 k (two uint4 per thread)
      int n = (tid >> 2) + p * 128, kq = tid & 3;
      *(uint4*)&Bs[n * LDT + kq * 8] = *(const uint4*)&Bt[(size_t)n * K + k0 + kq * 8];
    }
    __syncthreads();
    bf16x8 af[4], bfr[4];
#pragma unroll
    for (int m = 0; m < 4; ++m)
      af[m] = __builtin_bit_cast(
          bf16x8, *(const uint4*)&As[(wr * 64 + m * 16 + l15) * LDT + quad * 8]);
#pragma unroll
    for (int n = 0; n < 4; ++n)
      bfr[n] = __builtin_bit_cast(
          bf16x8, *(const uint4*)&Bs[(wc * 64 + n * 16 + l15) * LDT + quad * 8]);
#pragma unroll
    for (int m = 0; m < 4; ++m)
#pragma unroll
      for (int n = 0; n < 4; ++n)
        acc[m][n] = __builtin_amdgcn_mfma_f32_16x16x32_bf16(af[m], bfr[n], acc[m][n], 0, 0, 0);
    __syncthreads();
  }
  // epilogue: C/D map col=lane&15, row=(lane>>4)*4+reg
#pragma unroll
  for (int m = 0; m < 4; ++m) {
#pragma unroll
    for (int r = 0; r < 4; ++r) {
      int gr = row0 + wr * 64 + m * 16 + quad * 4 + r;
      if (gr >= M) continue;
      float sv = 1.0f;
      int bofs = 0;
      if (WRITE_U) {
        sv = inv_s[gr];
        bofs = batch[gr] * 256;
      }
#pragma unroll
      for (int n = 0; n < 4; ++n) {
        int cc = wc * 64 + n * 16 + l15;
        float v = acc[m][n][r] + bias[cc];
        if (RELU) v = fmaxf(v, 0.f);
        if (WRITE_U) {
          v = sv * (v + gh[bofs + cc]);
          unsigned pr = (unsigned)__builtin_amdgcn_cvt_pk_fp8_f32(v, v, 0, false);
          ((unsigned char*)outp)[(size_t)gr * 256 + cc] = (unsigned char)(pr & 0xffu);
        } else {
          ((unsigned short*)outp)[(size_t)gr * 256 + cc] = f2bf(v);
        }
      }
    }
  }
}

// ----------------------------- pool + final ---------------------------------

__global__ void pool_kernel(const unsigned short* __restrict__ h, const int* __restrict__ batch,
                            float* __restrict__ gmsum, float* __restrict__ cnt, int N, int chunk) {
  int start = blockIdx.x * chunk;
  int end = min(start + chunk, N);
  if (start >= end) return;
  int c = threadIdx.x;
  int g = batch[start];
  float acc = 0.0f;
  int run = 0;
  for (int n = start; n < end; ++n) {
    int bg = batch[n];
    if (bg != g) {
      atomicAdd(&gmsum[g * 256 + c], acc);
      if (c == 0) atomicAdd(&cnt[g], (float)run);
      acc = 0.0f;
      run = 0;
      g = bg;
    }
    acc += bf2f(h[(size_t)n * 256 + c]);
    run++;
  }
  atomicAdd(&gmsum[g * 256 + c], acc);
  if (c == 0) atomicAdd(&cnt[g], (float)run);
}

__global__ void final_kernel(const float* __restrict__ gmsum, const float* __restrict__ cnt,
                             const float* __restrict__ gh, const float* __restrict__ Wlin,
                             const float* __restrict__ blin, float* __restrict__ y,
                             float* __restrict__ gm_out, int G) {
  int g = blockIdx.x;
  int c = threadIdx.x;
  __shared__ float row[256];
  float v = gmsum[g * 256 + c] / fmaxf(cnt[g], 1.0f) + gh[g * 256 + c];
  gm_out[g * 256 + c] = v;
  row[c] = v;
  __syncthreads();
  if (c < 10) {
    float acc = blin[c];
    for (int k = 0; k < 256; ++k) acc += row[k] * Wlin[k * 10 + c];
    y[g * 10 + c] = acc;
  }
}

// ----------------------------- launch ----------------------------------------

extern "C" void kernel_launch(void* const* d_in, const int* in_sizes, int n_in,
                              void* d_out, int out_size, void* d_ws, size_t ws_size,
                              hipStream_t stream) {
  const float* x = (const float*)d_in[0];
  const int* ei = (const int*)d_in[1];
  const int* batch = (const int*)d_in[2];
  const float* gh = (const float*)d_in[3];
  const float* W0 = (const float*)d_in[4];
  const float* b0 = (const float*)d_in[5];
  const float* Ws = (const float*)d_in[6];
  const float* bs = (const float*)d_in[7];
  const float* Wlin = (const float*)d_in[8];
  const float* blin = (const float*)d_in[9];
  float* out = (float*)d_out;

  const int N = in_sizes[2];
  const int E = in_sizes[1] / 2;
  const int G = in_sizes[3] / 256;
  const int H = 256, L = 3, C = 10, F = 128;

  char* ws = (char*)d_ws;
  size_t off = 0;
  auto alloc = [&](size_t bytes) {
    void* p = ws + off;
    off += (bytes + 255) & ~(size_t)255;
    return p;
  };
  // NOTE: deg and cnt+gmsum are kept contiguous for merged memsets.
  size_t cntspan = ((size_t)G * 4 + 255) & ~(size_t)255;
  int* deg = (int*)alloc((size_t)N * 4);
  float* cnt = (float*)alloc((size_t)G * 4);
  float* gmsum = (float*)alloc((size_t)G * H * 4);
  int* row_off = (int*)alloc((size_t)(N + 1) * 4);
  int* bsum = (int*)alloc(256 * 4);
  int* boff = (int*)alloc(256 * 4);
  int* col = (int*)alloc((size_t)E * 4);
  unsigned short* pos = (unsigned short*)alloc((size_t)E * 2);
  float* inv_s = (float*)alloc((size_t)N * 4);
  unsigned char* u_x = (unsigned char*)alloc((size_t)N * F);         // fp8 s*x
  unsigned char* uA = (unsigned char*)alloc((size_t)N * H);          // fp8 s*(h+res)
  unsigned short* aggA = (unsigned short*)alloc((size_t)N * H * 2);  // bf16 agg out / GEMM A
  unsigned short* hfin = (unsigned short*)alloc((size_t)N * H * 2);  // final h bf16
  unsigned short* Wt0 = (unsigned short*)alloc((size_t)F * H * 2);   // [256][128]
  unsigned short* WtS = (unsigned short*)alloc((size_t)L * H * H * 2);

  const int* srcv = ei;
  const int* dstv = ei + E;

  hipMemsetAsync(deg, 0, (size_t)N * 4, stream);
  hipMemsetAsync(cnt, 0, cntspan + (size_t)G * H * 4, stream);  // cnt + gmsum

  int EB = (E + 255) / 256;
  int NB = (N + 255) / 256;
  count_pos_kernel<<<EB, 256, 0, stream>>>(dstv, deg, pos, E);
  scan_partial_kernel<<<NB, 256, 0, stream>>>(deg, inv_s, bsum, N);
  scan_block_kernel<<<1, 256, 0, stream>>>(bsum, boff, row_off, NB, N);
  scan_final_kernel<<<NB, 256, 0, stream>>>(deg, boff, row_off, N);
  fill_csr2_kernel<<<(E / 4 + 256) / 256 + 1, 256, 0, stream>>>(srcv, dstv, pos, row_off, col, E);

  int UXDW = N * (F / 4);
  int TW = F * H + 3 * H * H;
  prep_all_kernel<<<(UXDW + TW + 255) / 256, 256, 0, stream>>>(x, inv_s, (unsigned*)u_x, UXDW,
                                                               W0, Ws, Wt0, WtS);

  int AGG_GRID = (N + 3) / 4;
  int GEMM_GRID = (N + 127) / 128;

  // layer 0: agg(u_x fp8) -> GEMM K=128 (no relu) -> uA = fp8(s*(h0+res))
  aggregate_fp8_kernel<128><<<AGG_GRID, 256, 0, stream>>>(u_x, row_off, col, inv_s, aggA, N);
  gemm_kernel<128, false, true><<<GEMM_GRID, 512, 0, stream>>>(aggA, Wt0, b0, inv_s, batch, gh,
                                                               uA, N);
  // layers 1..2: agg(uA fp8) -> GEMM relu -> uA fp8
  for (int l = 0; l < 2; ++l) {
    aggregate_fp8_kernel<256><<<AGG_GRID, 256, 0, stream>>>(uA, row_off, col, inv_s, aggA, N);
    gemm_kernel<256, true, true><<<GEMM_GRID, 512, 0, stream>>>(
        aggA, WtS + (size_t)l * H * H, bs + (size_t)l * H, inv_s, batch, gh, uA, N);
  }
  // layer 3: agg(uA fp8) -> GEMM relu -> h (bf16)
  aggregate_fp8_kernel<256><<<AGG_GRID, 256, 0, stream>>>(uA, row_off, col, inv_s, aggA, N);
  gemm_kernel<256, true, false><<<GEMM_GRID, 512, 0, stream>>>(
      aggA, WtS + (size_t)2 * H * H, bs + (size_t)2 * H, inv_s, batch, gh, hfin, N);

  int PB = 1024;
  int chunk = (N + PB - 1) / PB;
  pool_kernel<<<PB, 256, 0, stream>>>(hfin, batch, gmsum, cnt, N, chunk);
  final_kernel<<<G, 256, 0, stream>>>(gmsum, cnt, gh, Wlin, blin, out, out + (size_t)G * C, G);
}